// Round 4
// baseline (1427.323 us; speedup 1.0000x reference)
//
#include <hip/hip_runtime.h>

#define D 64
constexpr int U_ = 50000, B_ = 20000, I_ = 40000;

// ---------------- CSR build (per call, per graph) ----------------

__global__ void k_hist(const int* __restrict__ rows, int nnz, int* __restrict__ cnt) {
    int e = blockIdx.x * blockDim.x + threadIdx.x;
    if (e < nnz) atomicAdd(&cnt[rows[e]], 1);
}

// Degree -> scale. mode 0: 1/(sqrt(deg)+1e-8)  (sym Laplacian factor)
//                  mode 1: 1/max(deg,1)        (row-normalized agg)
__global__ void k_scale(const int* __restrict__ cnt, int n,
                        float* __restrict__ scale, int mode) {
    int i = blockIdx.x * blockDim.x + threadIdx.x;
    if (i >= n) return;
    int c = cnt[i];
    scale[i] = (mode == 0) ? 1.0f / (sqrtf((float)c) + 1e-8f)
                           : 1.0f / (float)max(c, 1);
}

// Pass A: per-block sums over 1024-count tiles (256 thr x 4 counts).
__global__ void k_scanA(const int* __restrict__ cnt, int n, int* __restrict__ blksum) {
    __shared__ int sm[256];
    int t = threadIdx.x;
    int i0 = blockIdx.x * 1024 + t * 4;
    int s = 0;
    if (i0 + 3 < n) {
        int4 v = *(const int4*)(cnt + i0);
        s = v.x + v.y + v.z + v.w;
    } else {
        for (int k = 0; k < 4; k++) { int i = i0 + k; if (i < n) s += cnt[i]; }
    }
    sm[t] = s;
    __syncthreads();
    for (int off = 128; off; off >>= 1) {
        if (t < off) sm[t] += sm[t + off];
        __syncthreads();
    }
    if (t == 0) blksum[blockIdx.x] = sm[0];
}

// Pass B: single small block scans G (<=256) block sums -> exclusive offsets.
__global__ void k_scanB(int* __restrict__ blksum, int G) {
    __shared__ int sm[256];
    int t = threadIdx.x;
    sm[t] = (t < G) ? blksum[t] : 0;
    __syncthreads();
    for (int off = 1; off < 256; off <<= 1) {
        int v = (t >= off) ? sm[t - off] : 0;
        __syncthreads();
        sm[t] += v;
        __syncthreads();
    }
    if (t < G) blksum[t] = (t == 0) ? 0 : sm[t - 1];   // exclusive
}

// Pass C: intra-block exclusive scan + block offset -> rowstart & cursor.
__global__ void k_scanC(const int* __restrict__ cnt, int n,
                        const int* __restrict__ blkoff,
                        int* __restrict__ rowstart, int* __restrict__ cursor) {
    __shared__ int sm[256];
    int t = threadIdx.x;
    int i0 = blockIdx.x * 1024 + t * 4;
    int c0 = 0, c1 = 0, c2 = 0, c3 = 0;
    if (i0 + 3 < n) {
        int4 v = *(const int4*)(cnt + i0);
        c0 = v.x; c1 = v.y; c2 = v.z; c3 = v.w;
    } else {
        if (i0 + 0 < n) c0 = cnt[i0 + 0];
        if (i0 + 1 < n) c1 = cnt[i0 + 1];
        if (i0 + 2 < n) c2 = cnt[i0 + 2];
        if (i0 + 3 < n) c3 = cnt[i0 + 3];
    }
    int tsum = c0 + c1 + c2 + c3;
    sm[t] = tsum;
    __syncthreads();
    for (int off = 1; off < 256; off <<= 1) {
        int v = (t >= off) ? sm[t - off] : 0;
        __syncthreads();
        sm[t] += v;
        __syncthreads();
    }
    int run = blkoff[blockIdx.x] + ((t == 0) ? 0 : sm[t - 1]);
    int o0 = run, o1 = o0 + c0, o2 = o1 + c1, o3 = o2 + c2;
    if (i0 + 0 < n) { rowstart[i0 + 0] = o0; cursor[i0 + 0] = o0; if (i0 + 0 == n - 1) rowstart[n] = o0 + c0; }
    if (i0 + 1 < n) { rowstart[i0 + 1] = o1; cursor[i0 + 1] = o1; if (i0 + 1 == n - 1) rowstart[n] = o1 + c1; }
    if (i0 + 2 < n) { rowstart[i0 + 2] = o2; cursor[i0 + 2] = o2; if (i0 + 2 == n - 1) rowstart[n] = o2 + c2; }
    if (i0 + 3 < n) { rowstart[i0 + 3] = o3; cursor[i0 + 3] = o3; if (i0 + 3 == n - 1) rowstart[n] = o3 + c3; }
}

// Scatter col indices only (values are recomputed from degrees).
__global__ void k_scatter(const int* __restrict__ rows, const int* __restrict__ cols,
                          int nnz, int* __restrict__ cursor, int* __restrict__ ecol) {
    int e = blockIdx.x * blockDim.x + threadIdx.x;
    if (e >= nnz) return;
    int pos = atomicAdd(&cursor[rows[e]], 1);
    ecol[pos] = cols[e];
}

// ---------------- fused CSR-SpMM + scale + l2norm + acc ----------------
// One 64-lane wave per destination row. y[r] = s[r]*inv * sum s[c]*x[c].
// Epilogue: optional f write, l2-normalize via shfl reduce, acc init/accum.
__global__ void k_layer(const int* __restrict__ rowstart, const int* __restrict__ ecol,
                        const float* __restrict__ scale, int n, int nsplit,
                        const float* __restrict__ xA, const float* __restrict__ xB_adj,
                        float inv, float* __restrict__ fout, int write_f, int init,
                        float* __restrict__ accA, float* __restrict__ accB) {
    int row = (blockIdx.x << 2) + (threadIdx.x >> 6);
    if (row >= n) return;
    int lane = threadIdx.x & 63;
    int s = rowstart[row], e = rowstart[row + 1];
    float acc = 0.f;
    for (int base = s; base < e; base += 64) {
        int jn = e - base; if (jn > 64) jn = 64;
        int li = base + (lane < jn ? lane : jn - 1);   // clamped vector load
        int   cj = ecol[li];
        float vj = scale[cj];                          // L2-resident table gather
        for (int j = 0; j < jn; j++) {
            int   c = __shfl(cj, j, 64);
            float v = __shfl(vj, j, 64);
            const float* xp = (c < nsplit) ? xA : xB_adj;   // wave-uniform select
            acc += v * xp[(size_t)c * D + lane];
        }
    }
    float v = acc * scale[row] * inv;
    if (write_f) fout[(size_t)row * D + lane] = v;
    float sq = v * v;
    #pragma unroll
    for (int off = 32; off; off >>= 1) sq += __shfl_xor(sq, off, 64);
    float r = v / fmaxf(sqrtf(sq), 1e-12f);
    if (row < U_) {
        float* p = &accA[(size_t)row * D + lane];
        if (init) { const float* xr = (row < nsplit) ? xA : xB_adj;
                    *p = xr[(size_t)row * D + lane] + r; }
        else      *p += r;
    } else {
        float* p = &accB[(size_t)(row - U_) * D + lane];
        if (init) { const float* xr = (row < nsplit) ? xA : xB_adj;
                    *p = xr[(size_t)row * D + lane] + r; }
        else      *p += r;
    }
}

// Plain CSR-SpMM with row scaling (bundle aggregation): y[r] = rs[r]*sum x[c]
__global__ void k_spmm_csr(const int* __restrict__ rowstart, const int* __restrict__ ecol,
                           const float* __restrict__ rs, int n,
                           const float* __restrict__ x, float* __restrict__ y) {
    int row = (blockIdx.x << 2) + (threadIdx.x >> 6);
    if (row >= n) return;
    int lane = threadIdx.x & 63;
    int s = rowstart[row], e = rowstart[row + 1];
    float acc = 0.f;
    for (int base = s; base < e; base += 64) {
        int jn = e - base; if (jn > 64) jn = 64;
        int li = base + (lane < jn ? lane : jn - 1);
        int cj = ecol[li];
        for (int j = 0; j < jn; j++) {
            int c = __shfl(cj, j, 64);
            acc += x[(size_t)c * D + lane];
        }
    }
    y[(size_t)row * D + lane] = acc * rs[row];
}

extern "C" void kernel_launch(void* const* d_in, const int* in_sizes, int n_in,
                              void* d_out, int out_size, void* d_ws, size_t ws_size,
                              hipStream_t stream) {
    const float* users   = (const float*)d_in[0];
    const float* bundles = (const float*)d_in[1];
    const float* items   = (const float*)d_in[2];
    const int*   ui_idx  = (const int*)d_in[3];
    const int*   ub_idx  = (const int*)d_in[5];
    const int*   ubx_idx = (const int*)d_in[7];
    const int*   agg_idx = (const int*)d_in[9];
    const int ui_nnz  = in_sizes[4];
    const int ub_nnz  = in_sizes[6];
    const int ubx_nnz = in_sizes[8];
    const int agg_nnz = in_sizes[10];

    float* out = (float*)d_out;
    const size_t rowf = (size_t)D;

    // ---- workspace carve-up ----
    const size_t NMAX   = (size_t)(U_ + I_) * D;      // 5.76M floats
    const int    NNZMAX = 2000000;                    // ui graph (largest)
    const int    NROWMX = U_ + I_ + 1;
    float* gbuf    = (float*)d_ws;                    // 23.04 MB (layer-0 out)
    float* acc_itm = gbuf + NMAX;                     // 10.24 MB
    float* scale   = acc_itm + (size_t)I_ * D;        //  0.36 MB
    int*   ecol    = (int*)(scale + NROWMX);          //  8.0 MB
    int*   rowstart= ecol + NNZMAX;
    int*   cursor  = rowstart + NROWMX;
    int*   cnt     = cursor + NROWMX;
    int*   blksum  = cnt + NROWMX;                    //  1 KB

    // ---- output layout ----
    float* out_IL_u = out;
    float* out_BL_u = out + (size_t)U_ * rowf;
    float* out_XL_u = out + (size_t)2 * U_ * rowf;
    float* out_IL_b = out + (size_t)3 * U_ * rowf;
    float* out_BL_b = out + (size_t)3 * U_ * rowf + (size_t)B_ * rowf;
    float* out_XL_b = out + (size_t)3 * U_ * rowf + (size_t)2 * B_ * rowf;

    auto build_csr = [&](const int* idxp, int nnz, int n, int mode) {
        const int G = (n + 1023) / 1024;   // <= 88
        hipMemsetAsync(cnt, 0, (size_t)n * sizeof(int), stream);
        hipLaunchKernelGGL(k_hist, dim3((nnz + 255) / 256), dim3(256), 0, stream,
                           idxp, nnz, cnt);
        hipLaunchKernelGGL(k_scale, dim3((n + 255) / 256), dim3(256), 0, stream,
                           cnt, n, scale, mode);
        hipLaunchKernelGGL(k_scanA, dim3(G), dim3(256), 0, stream, cnt, n, blksum);
        hipLaunchKernelGGL(k_scanB, dim3(1), dim3(256), 0, stream, blksum, G);
        hipLaunchKernelGGL(k_scanC, dim3(G), dim3(256), 0, stream,
                           cnt, n, blksum, rowstart, cursor);
        hipLaunchKernelGGL(k_scatter, dim3((nnz + 255) / 256), dim3(256), 0, stream,
                           idxp, idxp + nnz, nnz, cursor, ecol);
    };

    auto propagate = [&](const int* idxp, int nnz,
                         const float* Bfeat, int nB, float* accA, float* accB) {
        const int n = U_ + nB;
        build_csr(idxp, nnz, n, 0);
        // layer 0: g = spmm(raw)/2 ; acc = raw + l2norm(g)
        hipLaunchKernelGGL(k_layer, dim3((n + 3) / 4), dim3(256), 0, stream,
                           rowstart, ecol, scale, n, U_,
                           users, Bfeat - (size_t)U_ * rowf,
                           0.5f, gbuf, 1, 1, accA, accB);
        // layer 1: f = spmm(g)/3 ; acc += l2norm(f)   (f never read -> no write)
        hipLaunchKernelGGL(k_layer, dim3((n + 3) / 4), dim3(256), 0, stream,
                           rowstart, ecol, scale, n, n,
                           gbuf, gbuf,
                           1.0f / 3.0f, (float*)nullptr, 0, 0, accA, accB);
    };

    // item-level propagation over user-item graph
    propagate(ui_idx, ui_nnz, items, I_, out_IL_u, acc_itm);

    // bundle aggregation: IL_b = agg @ IL_i   (row-normalized)
    build_csr(agg_idx, agg_nnz, B_, 1);
    hipLaunchKernelGGL(k_spmm_csr, dim3((B_ + 3) / 4), dim3(256), 0, stream,
                       rowstart, ecol, scale, B_, acc_itm, out_IL_b);

    // bundle-level propagation over user-bundle graph
    propagate(ub_idx, ub_nnz, bundles, B_, out_BL_u, out_BL_b);

    // ingredient-augmented user-bundle propagation
    propagate(ubx_idx, ubx_nnz, bundles, B_, out_XL_u, out_XL_b);
}